// Round 6
// baseline (1491.018 us; speedup 1.0000x reference)
//
#include <hip/hip_runtime.h>
#include <hip/hip_bf16.h>
#include <math.h>

#define D_MODEL 1024
#define SEQ 2048
#define BATCH 8

typedef unsigned short u16;
typedef __attribute__((ext_vector_type(8))) short bf16x8;
typedef __attribute__((ext_vector_type(4))) float f32x4;

__device__ inline u16 f2bf(float f) {
  __hip_bfloat16 h = __float2bfloat16(f);
  return __builtin_bit_cast(u16, h);
}
__device__ inline float bf2f(u16 u) {
  return __builtin_bit_cast(float, (unsigned)u << 16);
}

// async 16B global->LDS copy; LDS dest is wave-uniform base + lane*16
__device__ __forceinline__ void async_cp16(const u16* g, u16* l) {
  __builtin_amdgcn_global_load_lds(
      (const __attribute__((address_space(1))) void*)g,
      (__attribute__((address_space(3))) void*)l, 16, 0, 0);
}

// ---------------- LayerNorm: fp32 in -> bf16 out ----------------
__global__ __launch_bounds__(256) void ln_kernel(
    const float* __restrict__ x, const float* __restrict__ w,
    const float* __restrict__ b, u16* __restrict__ out) {
  int row = blockIdx.x;
  int t = threadIdx.x;
  const float4* xr = (const float4*)(x + (size_t)row * D_MODEL);
  float4 v = xr[t];
  float s = v.x + v.y + v.z + v.w;
  float s2 = v.x * v.x + v.y * v.y + v.z * v.z + v.w * v.w;
  for (int o = 32; o > 0; o >>= 1) {
    s += __shfl_down(s, o);
    s2 += __shfl_down(s2, o);
  }
  __shared__ float red[10];
  int wave = t >> 6, lane = t & 63;
  if (lane == 0) { red[wave] = s; red[4 + wave] = s2; }
  __syncthreads();
  if (t == 0) {
    float S = red[0] + red[1] + red[2] + red[3];
    float S2 = red[4] + red[5] + red[6] + red[7];
    float mu = S * (1.f / D_MODEL);
    float var = S2 * (1.f / D_MODEL) - mu * mu;
    red[8] = mu;
    red[9] = rsqrtf(var + 1e-5f);
  }
  __syncthreads();
  float mu = red[8], rstd = red[9];
  float4 w4 = ((const float4*)w)[t];
  float4 b4 = ((const float4*)b)[t];
  ushort4 o4;
  o4.x = f2bf((v.x - mu) * rstd * w4.x + b4.x);
  o4.y = f2bf((v.y - mu) * rstd * w4.y + b4.y);
  o4.z = f2bf((v.z - mu) * rstd * w4.z + b4.z);
  o4.w = f2bf((v.w - mu) * rstd * w4.w + b4.w);
  ((ushort4*)(out + (size_t)row * D_MODEL))[t] = o4;
}

// ---- Softmax over a 2048-wide bf16 row, IN PLACE (fp32 math) ----
__global__ __launch_bounds__(256) void softmax_bf16_kernel(u16* __restrict__ p) {
  int row = blockIdx.x;
  int t = threadIdx.x;
  int4 q = ((const int4*)(p + (size_t)row * SEQ))[t];
  u16 us[8];
  __builtin_memcpy(us, &q, 16);
  float vals[8];
  for (int i = 0; i < 8; i++) vals[i] = bf2f(us[i]);
  float m = vals[0];
  for (int i = 1; i < 8; i++) m = fmaxf(m, vals[i]);
  for (int o = 32; o > 0; o >>= 1) m = fmaxf(m, __shfl_down(m, o));
  __shared__ float red[6];
  int wave = t >> 6, lane = t & 63;
  if (lane == 0) red[wave] = m;
  __syncthreads();
  if (t == 0) red[4] = fmaxf(fmaxf(red[0], red[1]), fmaxf(red[2], red[3]));
  __syncthreads();
  m = red[4];
  float s = 0.f;
  for (int i = 0; i < 8; i++) { vals[i] = __expf(vals[i] - m); s += vals[i]; }
  for (int o = 32; o > 0; o >>= 1) s += __shfl_down(s, o);
  if (lane == 0) red[wave] = s;
  __syncthreads();
  if (t == 0) red[5] = red[0] + red[1] + red[2] + red[3];
  __syncthreads();
  float inv = 1.f / red[5];
  union { u16 us[8]; int4 v4; } pk;
  for (int i = 0; i < 8; i++) pk.us[i] = f2bf(vals[i] * inv);
  ((int4*)(p + (size_t)row * SEQ))[t] = pk.v4;
}

// ---- Weight fp32 [K,N] -> bf16 transposed [N,K], all 3 weights, 1 launch ----
// tiles: W_attn 16x48=768, W_fc 16x64=1024, W_proj 64x16=1024 => 2816 blocks
__global__ __launch_bounds__(256) void wconv_all(
    const float* __restrict__ Wa, const float* __restrict__ Wf,
    const float* __restrict__ Wp, u16* __restrict__ WaT,
    u16* __restrict__ WfT, u16* __restrict__ WpT) {
  int bid = blockIdx.x;
  const float* W;
  u16* Wt;
  int K, N, gx, local;
  if (bid < 768)       { W = Wa; Wt = WaT; K = 1024; N = 3072; gx = 16; local = bid; }
  else if (bid < 1792) { W = Wf; Wt = WfT; K = 1024; N = 4096; gx = 16; local = bid - 768; }
  else                 { W = Wp; Wt = WpT; K = 4096; N = 1024; gx = 64; local = bid - 1792; }
  int k0 = (local % gx) * 64, n0 = (local / gx) * 64;
  __shared__ u16 tile[64][65];
  int t = threadIdx.x;
  for (int p = 0; p < 16; p++) {
    int idx = p * 256 + t;
    int r = idx >> 6, c = idx & 63;
    tile[r][c] = f2bf(W[(size_t)(k0 + r) * N + n0 + c]);
  }
  __syncthreads();
  for (int p = 0; p < 16; p++) {
    int idx = p * 256 + t;
    int r = idx >> 6, c = idx & 63;
    Wt[(size_t)(n0 + r) * K + k0 + c] = tile[c][r];
  }
}

// ---- GEMM: C[M,N] = A[M,K] * Bt[N,K]^T, bf16 in, fp32 acc ----
// BK=64, async LDS staging, XOR bank-conflict swizzle.
// LDS tile [128][64] u16; physical col-group (16B) = logical ^ (row & 7).
// launch_bounds(256,5): 5 blocks/CU (LDS 160K/32K) deepens the m114-style
// inter-block overlap that hides the per-barrier vmcnt drain.
enum { EPI_QKV = 0, EPI_SCALE_BF16 = 1, EPI_RESID_F32 = 2,
       EPI_GELU_BF16 = 3, EPI_BIAS_F32 = 4 };

template <int EPI>
__global__ __launch_bounds__(256, 5) void gemm_bt(
    const u16* __restrict__ A, const u16* __restrict__ Bt,
    void* __restrict__ Cv, const float* __restrict__ bias,
    const float* __restrict__ resid, u16* __restrict__ vTp,
    int M, int N, int K, int lda, int ldb, int ldc, float scale,
    long long saB, long long sbB, long long scB, long long srB) {
  __shared__ __align__(16) u16 lA[128 * 64];
  __shared__ __align__(16) u16 lB[128 * 64];
  int t = threadIdx.x;
  int zb = blockIdx.z;
  A += (size_t)zb * saB;
  Bt += (size_t)zb * sbB;

  // tile-raster swizzle: 4 M-tiles per stripe, N fastest within stripe.
  int gx = gridDim.x;
  int flat = blockIdx.x + gx * blockIdx.y;
  int rem = flat % (4 * gx);
  int m0 = ((flat / (4 * gx)) * 4 + (rem & 3)) * 128;
  int n0 = (rem >> 2) * 128;

  int wv = t >> 6, lane = t & 63;

  // staging: 4 rounds per tile; round r covers rows r*32 + t/8, thread t
  // fetches global col-group (t&7) ^ ((t>>3)&7)  (XOR swizzle, key = row&7,
  // r*32 == 0 mod 8 so key is r-independent); LDS dest = r*2048 + t*8 u16.
  int srow = t >> 3;                       // 0..31
  int scg = (t & 7) ^ ((t >> 3) & 7);      // swizzled col-group
  int scol = scg << 3;                     // u16 offset within row
  const u16* gA = A + (size_t)(m0 + srow) * lda + scol;
  const u16* gB = Bt + (size_t)(n0 + srow) * ldb + scol;
  u16* lAd = lA + t * 8;
  u16* lBd = lB + t * 8;

  int wm = (wv >> 1) * 64, wn = (wv & 1) * 64;
  int lr = lane & 15, lq = lane >> 4;
  int keyr = lr & 7;                       // fragment-read swizzle key
  f32x4 acc[4][4] = {};

  for (int k0 = 0; k0 < K; k0 += 64) {
    #pragma unroll
    for (int r = 0; r < 4; r++) {
      async_cp16(gA + (size_t)(r * 32) * lda, lAd + r * 2048);
      async_cp16(gB + (size_t)(r * 32) * ldb, lBd + r * 2048);
    }
    gA += 64; gB += 64;
    __syncthreads();
    #pragma unroll
    for (int ks = 0; ks < 2; ks++) {
      bf16x8 af[4], bfr[4];
      #pragma unroll
      for (int i = 0; i < 4; i++)
        af[i] = *(const bf16x8*)(lA + (wm + i * 16 + lr) * 64 +
                                 (((lq + 4 * ks) ^ keyr) << 3));
      #pragma unroll
      for (int j = 0; j < 4; j++)
        bfr[j] = *(const bf16x8*)(lB + (wn + j * 16 + lr) * 64 +
                                  (((lq + 4 * ks) ^ keyr) << 3));
      #pragma unroll
      for (int i = 0; i < 4; i++)
        #pragma unroll
        for (int j = 0; j < 4; j++)
          acc[i][j] = __builtin_amdgcn_mfma_f32_16x16x32_bf16(
              af[i], bfr[j], acc[i][j], 0, 0, 0);
    }
    __syncthreads();
  }

  float* Cf = (float*)Cv + (size_t)zb * scB;
  u16* Ch = (u16*)Cv + (size_t)zb * scB;
  const float* rz = resid + (size_t)zb * srB;

  if constexpr (EPI == EPI_QKV) {
    if (n0 >= 2048) {
      // V columns: write transposed vT[b][d][s], 4 consecutive s per lane
      for (int i = 0; i < 4; i++) {
        int row0 = m0 + wm + i * 16 + lq * 4;
        int batch = row0 >> 11, s0 = row0 & 2047;
        for (int j = 0; j < 4; j++) {
          int d = n0 - 2048 + wn + j * 16 + lr;
          float bcol = bias[n0 + wn + j * 16 + lr];
          ushort4 o4;
          o4.x = f2bf(acc[i][j][0] + bcol);
          o4.y = f2bf(acc[i][j][1] + bcol);
          o4.z = f2bf(acc[i][j][2] + bcol);
          o4.w = f2bf(acc[i][j][3] + bcol);
          *(ushort4*)(vTp + (((size_t)batch * 1024 + d) << 11) + s0) = o4;
        }
      }
      return;
    }
  }

  for (int i = 0; i < 4; i++) {
    for (int j = 0; j < 4; j++) {
      int col = n0 + wn + j * 16 + lr;
      float bcol = (EPI == EPI_QKV || EPI == EPI_GELU_BF16 ||
                    EPI == EPI_BIAS_F32) ? bias[col] : 0.f;
      for (int r = 0; r < 4; r++) {
        int row = m0 + wm + i * 16 + lq * 4 + r;
        float v = acc[i][j][r];
        size_t off = (size_t)row * ldc + col;
        if constexpr (EPI == EPI_QKV) {
          Ch[off] = f2bf(v + bcol);
        } else if constexpr (EPI == EPI_SCALE_BF16) {
          Ch[off] = f2bf(v * scale);
        } else if constexpr (EPI == EPI_RESID_F32) {
          Cf[off] = v + rz[off];
        } else if constexpr (EPI == EPI_GELU_BF16) {
          float xx = v + bcol;
          // tanh-approx GELU
          float u = xx * (0.7978845608f + 0.0356774081f * xx * xx);
          float e = __expf(2.f * u);
          float th = 1.f - 2.f * __builtin_amdgcn_rcpf(e + 1.f);
          Ch[off] = f2bf(0.5f * xx * (1.f + th));
        } else {
          Cf[off] = v + bcol;
        }
      }
    }
  }
}

extern "C" void kernel_launch(void* const* d_in, const int* in_sizes, int n_in,
                              void* d_out, int out_size, void* d_ws, size_t ws_size,
                              hipStream_t stream) {
  const float* x      = (const float*)d_in[0];
  const float* ln1_w  = (const float*)d_in[1];
  const float* ln1_b  = (const float*)d_in[2];
  const float* W_attn = (const float*)d_in[3];
  const float* b_attn = (const float*)d_in[4];
  const float* ln2_w  = (const float*)d_in[5];
  const float* ln2_b  = (const float*)d_in[6];
  const float* W_fc   = (const float*)d_in[7];
  const float* b_fc   = (const float*)d_in[8];
  const float* W_proj = (const float*)d_in[9];
  const float* b_proj = (const float*)d_in[10];
  float* out = (float*)d_out;

  // Workspace layout, peak 190,840,832 B (~182 MiB). Liveness-checked:
  //   qk  [0,64M):    QKV out (q cols 0..1023, k cols 1024..2047); dead after scores
  //   vT  [64M,96M):  V transposed [8][1024][2048]; dead after PV
  //   hb1 [96M,128M): LN1 out; dead after QKV (sc clobbers it)
  //   sc  [96M,160M): FULL scores [8][2048][2048] bf16; single-pass attention
  //   hb2 [128M,160M): LN2 out (sc dead by then)
  //   fc  [0,128M):   FC out (qk+vT dead by then)
  //   [160M,182M):    bf16 transposed weights (live whole launch)
  // Residual (x + attn) lives fp32 in d_out until Proj overwrites it.
  if (ws_size < 190840832ull) return;
  char* ws = (char*)d_ws;
  u16* qk   = (u16*)(ws + 0);
  u16* vT   = (u16*)(ws + 67108864ull);
  u16* hb1  = (u16*)(ws + 100663296ull);
  u16* sc   = (u16*)(ws + 100663296ull);
  u16* hb2  = (u16*)(ws + 134217728ull);
  u16* fc   = (u16*)(ws + 0);
  u16* WaT  = (u16*)(ws + 167772160ull);
  u16* WfT  = (u16*)(ws + 174063616ull);
  u16* WpT  = (u16*)(ws + 182452224ull);

  wconv_all<<<2816, 256, 0, stream>>>(W_attn, W_fc, W_proj, WaT, WfT, WpT);

  ln_kernel<<<BATCH * SEQ, 256, 0, stream>>>(x, ln1_w, ln1_b, hb1);

  // QKV: [16384,1024] @ [1024,3072] + b; q,k -> qk (ldc 2048), v -> vT transposed
  gemm_bt<EPI_QKV><<<dim3(24, 128, 1), 256, 0, stream>>>(
      hb1, WaT, qk, b_attn, x, vT, BATCH * SEQ, 3072, 1024, 1024, 1024, 2048, 1.f,
      0, 0, 0, 0);

  // Attention single-pass over all 8 batches (gridDim.z = 8)
  const float iss = 0.03125f;  // 1/sqrt(1024)
  gemm_bt<EPI_SCALE_BF16><<<dim3(16, 16, 8), 256, 0, stream>>>(
      qk, qk + 1024, sc, nullptr, x, nullptr, SEQ, SEQ, 1024, 2048, 2048, SEQ,
      iss, (long long)SEQ * 2048, (long long)SEQ * 2048, (long long)SEQ * SEQ, 0);
  softmax_bf16_kernel<<<BATCH * SEQ, 256, 0, stream>>>(sc);
  // PV: 1024 blocks = exactly 4 blocks/CU
  gemm_bt<EPI_RESID_F32><<<dim3(8, 16, 8), 256, 0, stream>>>(
      sc, vT, out, nullptr, x, nullptr, SEQ, D_MODEL, SEQ,
      SEQ, SEQ, D_MODEL, 1.f,
      (long long)SEQ * SEQ, (long long)D_MODEL * SEQ,
      (long long)SEQ * D_MODEL, (long long)SEQ * D_MODEL);

  // LN2: out (fp32 residual) -> hb2
  ln_kernel<<<BATCH * SEQ, 256, 0, stream>>>(out, ln2_w, ln2_b, hb2);

  // FC + GELU: [16384,1024] @ [1024,4096] -> bf16
  gemm_bt<EPI_GELU_BF16><<<dim3(32, 128, 1), 256, 0, stream>>>(
      hb2, WfT, fc, b_fc, x, nullptr, BATCH * SEQ, 4096, 1024, 1024, 1024, 4096,
      1.f, 0, 0, 0, 0);

  // Proj: [16384,4096] @ [4096,1024] + b -> fp32 out
  gemm_bt<EPI_BIAS_F32><<<dim3(8, 128, 1), 256, 0, stream>>>(
      fc, WpT, out, b_proj, x, nullptr, BATCH * SEQ, 1024, 4096, 4096, 4096,
      1024, 1.f, 0, 0, 0, 0);
}

// Round 7
// 730.772 us; speedup vs baseline: 2.0403x; 2.0403x over previous
//
#include <hip/hip_runtime.h>
#include <hip/hip_bf16.h>
#include <math.h>

#define D_MODEL 1024
#define SEQ 2048
#define BATCH 8

typedef unsigned short u16;
typedef __attribute__((ext_vector_type(8))) short bf16x8;
typedef __attribute__((ext_vector_type(4))) float f32x4;

__device__ inline u16 f2bf(float f) {
  __hip_bfloat16 h = __float2bfloat16(f);
  return __builtin_bit_cast(u16, h);
}
__device__ inline float bf2f(u16 u) {
  return __builtin_bit_cast(float, (unsigned)u << 16);
}

// async 16B global->LDS copy; LDS dest is wave-uniform base + lane*16
__device__ __forceinline__ void async_cp16(const u16* g, u16* l) {
  __builtin_amdgcn_global_load_lds(
      (const __attribute__((address_space(1))) void*)g,
      (__attribute__((address_space(3))) void*)l, 16, 0, 0);
}

// ---------------- LayerNorm: fp32 in -> bf16 out ----------------
__global__ __launch_bounds__(256) void ln_kernel(
    const float* __restrict__ x, const float* __restrict__ w,
    const float* __restrict__ b, u16* __restrict__ out) {
  int row = blockIdx.x;
  int t = threadIdx.x;
  const float4* xr = (const float4*)(x + (size_t)row * D_MODEL);
  float4 v = xr[t];
  float s = v.x + v.y + v.z + v.w;
  float s2 = v.x * v.x + v.y * v.y + v.z * v.z + v.w * v.w;
  for (int o = 32; o > 0; o >>= 1) {
    s += __shfl_down(s, o);
    s2 += __shfl_down(s2, o);
  }
  __shared__ float red[10];
  int wave = t >> 6, lane = t & 63;
  if (lane == 0) { red[wave] = s; red[4 + wave] = s2; }
  __syncthreads();
  if (t == 0) {
    float S = red[0] + red[1] + red[2] + red[3];
    float S2 = red[4] + red[5] + red[6] + red[7];
    float mu = S * (1.f / D_MODEL);
    float var = S2 * (1.f / D_MODEL) - mu * mu;
    red[8] = mu;
    red[9] = rsqrtf(var + 1e-5f);
  }
  __syncthreads();
  float mu = red[8], rstd = red[9];
  float4 w4 = ((const float4*)w)[t];
  float4 b4 = ((const float4*)b)[t];
  ushort4 o4;
  o4.x = f2bf((v.x - mu) * rstd * w4.x + b4.x);
  o4.y = f2bf((v.y - mu) * rstd * w4.y + b4.y);
  o4.z = f2bf((v.z - mu) * rstd * w4.z + b4.z);
  o4.w = f2bf((v.w - mu) * rstd * w4.w + b4.w);
  ((ushort4*)(out + (size_t)row * D_MODEL))[t] = o4;
}

// ---- Softmax over a 2048-wide bf16 row, IN PLACE (fp32 math) ----
__global__ __launch_bounds__(256) void softmax_bf16_kernel(u16* __restrict__ p) {
  int row = blockIdx.x;
  int t = threadIdx.x;
  int4 q = ((const int4*)(p + (size_t)row * SEQ))[t];
  u16 us[8];
  __builtin_memcpy(us, &q, 16);
  float vals[8];
  for (int i = 0; i < 8; i++) vals[i] = bf2f(us[i]);
  float m = vals[0];
  for (int i = 1; i < 8; i++) m = fmaxf(m, vals[i]);
  for (int o = 32; o > 0; o >>= 1) m = fmaxf(m, __shfl_down(m, o));
  __shared__ float red[6];
  int wave = t >> 6, lane = t & 63;
  if (lane == 0) red[wave] = m;
  __syncthreads();
  if (t == 0) red[4] = fmaxf(fmaxf(red[0], red[1]), fmaxf(red[2], red[3]));
  __syncthreads();
  m = red[4];
  float s = 0.f;
  for (int i = 0; i < 8; i++) { vals[i] = __expf(vals[i] - m); s += vals[i]; }
  for (int o = 32; o > 0; o >>= 1) s += __shfl_down(s, o);
  if (lane == 0) red[wave] = s;
  __syncthreads();
  if (t == 0) red[5] = red[0] + red[1] + red[2] + red[3];
  __syncthreads();
  float inv = 1.f / red[5];
  union { u16 us[8]; int4 v4; } pk;
  for (int i = 0; i < 8; i++) pk.us[i] = f2bf(vals[i] * inv);
  ((int4*)(p + (size_t)row * SEQ))[t] = pk.v4;
}

// ---- Weight fp32 [K,N] -> bf16 transposed [N,K], all 3 weights, 1 launch ----
// tiles: W_attn 16x48=768, W_fc 16x64=1024, W_proj 64x16=1024 => 2816 blocks
__global__ __launch_bounds__(256) void wconv_all(
    const float* __restrict__ Wa, const float* __restrict__ Wf,
    const float* __restrict__ Wp, u16* __restrict__ WaT,
    u16* __restrict__ WfT, u16* __restrict__ WpT) {
  int bid = blockIdx.x;
  const float* W;
  u16* Wt;
  int K, N, gx, local;
  if (bid < 768)       { W = Wa; Wt = WaT; K = 1024; N = 3072; gx = 16; local = bid; }
  else if (bid < 1792) { W = Wf; Wt = WfT; K = 1024; N = 4096; gx = 16; local = bid - 768; }
  else                 { W = Wp; Wt = WpT; K = 4096; N = 1024; gx = 64; local = bid - 1792; }
  int k0 = (local % gx) * 64, n0 = (local / gx) * 64;
  __shared__ u16 tile[64][65];
  int t = threadIdx.x;
  for (int p = 0; p < 16; p++) {
    int idx = p * 256 + t;
    int r = idx >> 6, c = idx & 63;
    tile[r][c] = f2bf(W[(size_t)(k0 + r) * N + n0 + c]);
  }
  __syncthreads();
  for (int p = 0; p < 16; p++) {
    int idx = p * 256 + t;
    int r = idx >> 6, c = idx & 63;
    Wt[(size_t)(n0 + r) * K + k0 + c] = tile[c][r];
  }
}

// ---- GEMM: C[M,N] = A[M,K] * Bt[N,K]^T, bf16 in, fp32 acc ----
// BK=64, async LDS staging, XOR bank-conflict swizzle.
// LDS tile [128][64] u16; physical col-group (16B) = logical ^ (row & 7).
// launch_bounds(256,4): DO NOT raise to 5 — the 2nd arg caps the unified
// VGPR budget at ~512/waves; 5 waves/EU forced VGPR<=96 and spilled the
// 64-reg accumulator to scratch (r6: WRITE_SIZE 131->917 MB, 146->345 us).
enum { EPI_QKV = 0, EPI_SCALE_BF16 = 1, EPI_RESID_F32 = 2,
       EPI_GELU_BF16 = 3, EPI_BIAS_F32 = 4 };

template <int EPI>
__global__ __launch_bounds__(256, 4) void gemm_bt(
    const u16* __restrict__ A, const u16* __restrict__ Bt,
    void* __restrict__ Cv, const float* __restrict__ bias,
    const float* __restrict__ resid, u16* __restrict__ vTp,
    int M, int N, int K, int lda, int ldb, int ldc, float scale,
    long long saB, long long sbB, long long scB, long long srB) {
  __shared__ __align__(16) u16 lA[128 * 64];
  __shared__ __align__(16) u16 lB[128 * 64];
  int t = threadIdx.x;
  int zb = blockIdx.z;
  A += (size_t)zb * saB;
  Bt += (size_t)zb * sbB;

  // tile-raster swizzle: 4 M-tiles per stripe, N fastest within stripe.
  int gx = gridDim.x;
  int flat = blockIdx.x + gx * blockIdx.y;
  int rem = flat % (4 * gx);
  int m0 = ((flat / (4 * gx)) * 4 + (rem & 3)) * 128;
  int n0 = (rem >> 2) * 128;

  int wv = t >> 6, lane = t & 63;

  // staging: 4 rounds per tile; round r covers rows r*32 + t/8, thread t
  // fetches global col-group (t&7) ^ ((t>>3)&7)  (XOR swizzle, key = row&7,
  // r*32 == 0 mod 8 so key is r-independent); LDS dest = r*2048 + t*8 u16.
  int srow = t >> 3;                       // 0..31
  int scg = (t & 7) ^ ((t >> 3) & 7);      // swizzled col-group
  int scol = scg << 3;                     // u16 offset within row
  const u16* gA = A + (size_t)(m0 + srow) * lda + scol;
  const u16* gB = Bt + (size_t)(n0 + srow) * ldb + scol;
  u16* lAd = lA + t * 8;
  u16* lBd = lB + t * 8;

  int wm = (wv >> 1) * 64, wn = (wv & 1) * 64;
  int lr = lane & 15, lq = lane >> 4;
  int keyr = lr & 7;                       // fragment-read swizzle key
  f32x4 acc[4][4] = {};

  for (int k0 = 0; k0 < K; k0 += 64) {
    #pragma unroll
    for (int r = 0; r < 4; r++) {
      async_cp16(gA + (size_t)(r * 32) * lda, lAd + r * 2048);
      async_cp16(gB + (size_t)(r * 32) * ldb, lBd + r * 2048);
    }
    gA += 64; gB += 64;
    __syncthreads();
    #pragma unroll
    for (int ks = 0; ks < 2; ks++) {
      bf16x8 af[4], bfr[4];
      #pragma unroll
      for (int i = 0; i < 4; i++)
        af[i] = *(const bf16x8*)(lA + (wm + i * 16 + lr) * 64 +
                                 (((lq + 4 * ks) ^ keyr) << 3));
      #pragma unroll
      for (int j = 0; j < 4; j++)
        bfr[j] = *(const bf16x8*)(lB + (wn + j * 16 + lr) * 64 +
                                  (((lq + 4 * ks) ^ keyr) << 3));
      #pragma unroll
      for (int i = 0; i < 4; i++)
        #pragma unroll
        for (int j = 0; j < 4; j++)
          acc[i][j] = __builtin_amdgcn_mfma_f32_16x16x32_bf16(
              af[i], bfr[j], acc[i][j], 0, 0, 0);
    }
    __syncthreads();
  }

  float* Cf = (float*)Cv + (size_t)zb * scB;
  u16* Ch = (u16*)Cv + (size_t)zb * scB;
  const float* rz = resid + (size_t)zb * srB;

  if constexpr (EPI == EPI_QKV) {
    if (n0 >= 2048) {
      // V columns: write transposed vT[b][d][s], 4 consecutive s per lane
      for (int i = 0; i < 4; i++) {
        int row0 = m0 + wm + i * 16 + lq * 4;
        int batch = row0 >> 11, s0 = row0 & 2047;
        for (int j = 0; j < 4; j++) {
          int d = n0 - 2048 + wn + j * 16 + lr;
          float bcol = bias[n0 + wn + j * 16 + lr];
          ushort4 o4;
          o4.x = f2bf(acc[i][j][0] + bcol);
          o4.y = f2bf(acc[i][j][1] + bcol);
          o4.z = f2bf(acc[i][j][2] + bcol);
          o4.w = f2bf(acc[i][j][3] + bcol);
          *(ushort4*)(vTp + (((size_t)batch * 1024 + d) << 11) + s0) = o4;
        }
      }
      return;
    }
  }

  for (int i = 0; i < 4; i++) {
    for (int j = 0; j < 4; j++) {
      int col = n0 + wn + j * 16 + lr;
      float bcol = (EPI == EPI_QKV || EPI == EPI_GELU_BF16 ||
                    EPI == EPI_BIAS_F32) ? bias[col] : 0.f;
      for (int r = 0; r < 4; r++) {
        int row = m0 + wm + i * 16 + lq * 4 + r;
        float v = acc[i][j][r];
        size_t off = (size_t)row * ldc + col;
        if constexpr (EPI == EPI_QKV) {
          Ch[off] = f2bf(v + bcol);
        } else if constexpr (EPI == EPI_SCALE_BF16) {
          Ch[off] = f2bf(v * scale);
        } else if constexpr (EPI == EPI_RESID_F32) {
          Cf[off] = v + rz[off];
        } else if constexpr (EPI == EPI_GELU_BF16) {
          float xx = v + bcol;
          // tanh-approx GELU
          float u = xx * (0.7978845608f + 0.0356774081f * xx * xx);
          float e = __expf(2.f * u);
          float th = 1.f - 2.f * __builtin_amdgcn_rcpf(e + 1.f);
          Ch[off] = f2bf(0.5f * xx * (1.f + th));
        } else {
          Cf[off] = v + bcol;
        }
      }
    }
  }
}

extern "C" void kernel_launch(void* const* d_in, const int* in_sizes, int n_in,
                              void* d_out, int out_size, void* d_ws, size_t ws_size,
                              hipStream_t stream) {
  const float* x      = (const float*)d_in[0];
  const float* ln1_w  = (const float*)d_in[1];
  const float* ln1_b  = (const float*)d_in[2];
  const float* W_attn = (const float*)d_in[3];
  const float* b_attn = (const float*)d_in[4];
  const float* ln2_w  = (const float*)d_in[5];
  const float* ln2_b  = (const float*)d_in[6];
  const float* W_fc   = (const float*)d_in[7];
  const float* b_fc   = (const float*)d_in[8];
  const float* W_proj = (const float*)d_in[9];
  const float* b_proj = (const float*)d_in[10];
  float* out = (float*)d_out;

  // Workspace layout, peak 190,840,832 B (~182 MiB). Liveness-checked:
  //   qk  [0,64M):    QKV out (q cols 0..1023, k cols 1024..2047); dead after scores
  //   vT  [64M,96M):  V transposed [8][1024][2048]; dead after PV
  //   hb1 [96M,128M): LN1 out; dead after QKV (sc clobbers it)
  //   sc  [96M,160M): FULL scores [8][2048][2048] bf16; single-pass attention
  //   hb2 [128M,160M): LN2 out (sc dead by then)
  //   fc  [0,128M):   FC out (qk+vT dead by then)
  //   [160M,182M):    bf16 transposed weights (live whole launch)
  // Residual (x + attn) lives fp32 in d_out until Proj overwrites it.
  if (ws_size < 190840832ull) return;
  char* ws = (char*)d_ws;
  u16* qk   = (u16*)(ws + 0);
  u16* vT   = (u16*)(ws + 67108864ull);
  u16* hb1  = (u16*)(ws + 100663296ull);
  u16* sc   = (u16*)(ws + 100663296ull);
  u16* hb2  = (u16*)(ws + 134217728ull);
  u16* fc   = (u16*)(ws + 0);
  u16* WaT  = (u16*)(ws + 167772160ull);
  u16* WfT  = (u16*)(ws + 174063616ull);
  u16* WpT  = (u16*)(ws + 182452224ull);

  wconv_all<<<2816, 256, 0, stream>>>(W_attn, W_fc, W_proj, WaT, WfT, WpT);

  ln_kernel<<<BATCH * SEQ, 256, 0, stream>>>(x, ln1_w, ln1_b, hb1);

  // QKV: [16384,1024] @ [1024,3072] + b; q,k -> qk (ldc 2048), v -> vT transposed
  gemm_bt<EPI_QKV><<<dim3(24, 128, 1), 256, 0, stream>>>(
      hb1, WaT, qk, b_attn, x, vT, BATCH * SEQ, 3072, 1024, 1024, 1024, 2048, 1.f,
      0, 0, 0, 0);

  // Attention single-pass over all 8 batches (gridDim.z = 8)
  const float iss = 0.03125f;  // 1/sqrt(1024)
  gemm_bt<EPI_SCALE_BF16><<<dim3(16, 16, 8), 256, 0, stream>>>(
      qk, qk + 1024, sc, nullptr, x, nullptr, SEQ, SEQ, 1024, 2048, 2048, SEQ,
      iss, (long long)SEQ * 2048, (long long)SEQ * 2048, (long long)SEQ * SEQ, 0);
  softmax_bf16_kernel<<<BATCH * SEQ, 256, 0, stream>>>(sc);
  // PV: 1024 blocks = exactly 4 blocks/CU
  gemm_bt<EPI_RESID_F32><<<dim3(8, 16, 8), 256, 0, stream>>>(
      sc, vT, out, nullptr, x, nullptr, SEQ, D_MODEL, SEQ,
      SEQ, SEQ, D_MODEL, 1.f,
      (long long)SEQ * SEQ, (long long)D_MODEL * SEQ,
      (long long)SEQ * D_MODEL, (long long)SEQ * D_MODEL);

  // LN2: out (fp32 residual) -> hb2
  ln_kernel<<<BATCH * SEQ, 256, 0, stream>>>(out, ln2_w, ln2_b, hb2);

  // FC + GELU: [16384,1024] @ [1024,4096] -> bf16
  gemm_bt<EPI_GELU_BF16><<<dim3(32, 128, 1), 256, 0, stream>>>(
      hb2, WfT, fc, b_fc, x, nullptr, BATCH * SEQ, 4096, 1024, 1024, 1024, 4096,
      1.f, 0, 0, 0, 0);

  // Proj: [16384,4096] @ [4096,1024] + b -> fp32 out
  gemm_bt<EPI_BIAS_F32><<<dim3(8, 128, 1), 256, 0, stream>>>(
      fc, WpT, out, b_proj, x, nullptr, BATCH * SEQ, 1024, 4096, 4096, 4096,
      1024, 1.f, 0, 0, 0, 0);
}